// Round 9
// baseline (449.666 us; speedup 1.0000x reference)
//
#include <hip/hip_runtime.h>
#include <hip/hip_bf16.h>
#include <hip/hip_cooperative_groups.h>

namespace cg = cooperative_groups;

#define NNODES 50000
#define NEDGES 800000
#define ETOT   850000
#define NEG_SLOPE 0.2f
#define LN_EPS 1e-5f
#define SM_EPS 1e-16f
#define NBUCK 196                 // ceil(50000/256) buckets of 256 nodes
#define NBLK 208                  // ceil(850000/4096) edge chunks
#define CHUNK 4096
#define COOPB 256                 // cooperative grid: 256 blocks x 256 threads

typedef short bf16x8 __attribute__((ext_vector_type(8)));
typedef float f32x4  __attribute__((ext_vector_type(4)));
typedef float v2f    __attribute__((ext_vector_type(2)));

__device__ __forceinline__ unsigned pack_bf2(float a, float b) {
    __hip_bfloat162 p;
    p.x = __float2bfloat16(a);
    p.y = __float2bfloat16(b);
    return *reinterpret_cast<unsigned*>(&p);
}

__device__ __forceinline__ v2f bf2_to_f2(unsigned u) {
    v2f r;
    r.x = __int_as_float((int)(u << 16));
    r.y = __int_as_float((int)(u & 0xFFFF0000u));
    return r;
}

template <int CTRL>
__device__ __forceinline__ float dpp_add(float x) {
    return x + __int_as_float(__builtin_amdgcn_update_dpp(
        0, __float_as_int(x), CTRL, 0xF, 0xF, true));
}
__device__ __forceinline__ float red16(float x) {
    x = dpp_add<0xB1>(x);
    x = dpp_add<0x4E>(x);
    x = dpp_add<0x124>(x);
    x = dpp_add<0x128>(x);
    return x;
}

__device__ __forceinline__ float edot2(v2f x01, v2f x23, v2f xr01, v2f xr23,
                                       v2f a01, v2f a23) {
    v2f s01 = x01 + xr01;
    v2f s23 = x23 + xr23;
    v2f t01 = __builtin_elementwise_max(s01, s01 * NEG_SLOPE);
    v2f t23 = __builtin_elementwise_max(s23, s23 * NEG_SLOPE);
    v2f d = t01 * a01 + t23 * a23;
    return d.x + d.y;
}

// XOR-swizzled LDS offset for 64-col short tiles (16B granules)
__device__ __forceinline__ int sw(int row, int c8) {
    return (row << 6) + ((c8 ^ (row & 7)) << 3);
}

// ================= ONE cooperative kernel: full CSR build + weight cast =========
// Phases: A cast+hist | B seg-scan | C top-scan | D add | E bscatter | F nfinal.
// 256 blocks x 256 thr (1 block/CU worst-case: trivially co-resident).
// Replaces 6 launches; 5 grid syncs.
__global__ void __launch_bounds__(256) k_csr_coop(
        const float* __restrict__ W1l, const float* __restrict__ W1r,
        const float* __restrict__ W2l, const float* __restrict__ W2r,
        __hip_bfloat16* __restrict__ w1lT, __hip_bfloat16* __restrict__ w1rT,
        __hip_bfloat16* __restrict__ w2lT, __hip_bfloat16* __restrict__ w2rT,
        unsigned short* __restrict__ csr_src, int* __restrict__ rowstart,
        const int* __restrict__ ei, int* __restrict__ part,
        unsigned* __restrict__ pairs, int* __restrict__ blocksum) {
    cg::grid_group grid = cg::this_grid();
    __shared__ int h[256];
    __shared__ int cur[256];
    const int bid = blockIdx.x;
    const int t = threadIdx.x;

    // ---- Phase A: weight cast (stride loop) + csr pad + per-(bucket,chunk) hist
    {
        int g0 = bid * 256 + t;
        if (g0 < 16) csr_src[ETOT + g0] = 0;     // pad: node-0 reads, weight-masked
        if (g0 == 16) rowstart[NNODES] = ETOT;   // sentinel
        for (int w = g0; w < 139264; w += COOPB * 256) {
            if (w < 65536) {
                int k = w >> 8, n = w & 255;
                w1lT[n * 256 + k] = __float2bfloat16(W1l[w]);
            } else if (w < 131072) {
                int u = w - 65536; int k = u >> 8, n = u & 255;
                w1rT[n * 256 + k] = __float2bfloat16(W1r[u]);
            } else if (w < 135168) {
                int u = w - 131072; int k = u >> 6, n = u & 63;
                w2lT[n * 64 + k] = __float2bfloat16(W2l[u]);
            } else {
                int u = w - 135168; int k = u >> 6, n = u & 63;
                w2rT[n * 64 + k] = __float2bfloat16(W2r[u]);
            }
        }
        if (bid < NBLK) {
            h[t] = 0;
            __syncthreads();
            const int base = bid * CHUNK;
            #pragma unroll
            for (int it = 0; it < 16; ++it) {
                int e = base + it * 256 + t;
                if (e < ETOT) {
                    int dst = (e < NEDGES) ? ei[NEDGES + e] : (e - NEDGES);
                    atomicAdd(&h[dst >> 8], 1);
                }
            }
            __syncthreads();
            part[t * NBLK + bid] = h[t];   // bucket-major
        }
    }
    grid.sync();

    // ---- Phase B: per-segment exclusive scan of part (208 segs of 256), in place
    if (bid < NBLK) {
        int idx = bid * 256 + t;
        int v = part[idx];
        h[t] = v;
        __syncthreads();
        #pragma unroll
        for (int off = 1; off < 256; off <<= 1) {
            int add = (t >= off) ? h[t - off] : 0;
            __syncthreads();
            h[t] += add;
            __syncthreads();
        }
        part[idx] = h[t] - v;
        if (t == 255) blocksum[bid] = h[255];
    }
    grid.sync();

    // ---- Phase C: scan blocksum (208 <= 256) on block 0
    if (bid == 0) {
        int v = (t < NBLK) ? blocksum[t] : 0;
        h[t] = v;
        __syncthreads();
        #pragma unroll
        for (int off = 1; off < 256; off <<= 1) {
            int add = (t >= off) ? h[t - off] : 0;
            __syncthreads();
            h[t] += add;
            __syncthreads();
        }
        if (t < NBLK) blocksum[t] = h[t] - v;
    }
    grid.sync();

    // ---- Phase D: add segment offsets (53248 = 208*256 elements)
    if (bid < NBLK) {
        int idx = bid * 256 + t;
        part[idx] += blocksum[idx >> 8];
    }
    grid.sync();

    // ---- Phase E: bucket scatter, LDS cursors, coalesced-run pair writes
    if (bid < NBLK) {
        cur[t] = part[t * NBLK + bid];
        __syncthreads();
        const int base = bid * CHUNK;
        #pragma unroll
        for (int it = 0; it < 16; ++it) {
            int e = base + it * 256 + t;
            if (e < ETOT) {
                int dst, src;
                if (e < NEDGES) { dst = ei[NEDGES + e]; src = ei[e]; }
                else            { dst = e - NEDGES;     src = dst; }
                int pos = atomicAdd(&cur[dst >> 8], 1);
                pairs[pos] = ((unsigned)dst << 16) | (unsigned)src;
            }
        }
    }
    grid.sync();

    // ---- Phase F: per-bucket count + LDS scan + rowstart + scatter to csr_src
    if (bid < NBUCK) {
        const int r0 = part[bid * NBLK];
        const int r1 = part[(bid + 1) * NBLK];
        h[t] = 0;
        __syncthreads();
        for (int i = r0 + t; i < r1; i += 1024) {
            unsigned p0 = pairs[i];
            bool v1 = (i + 256 < r1), v2 = (i + 512 < r1), v3 = (i + 768 < r1);
            unsigned p1 = v1 ? pairs[i + 256] : 0u;
            unsigned p2 = v2 ? pairs[i + 512] : 0u;
            unsigned p3 = v3 ? pairs[i + 768] : 0u;
            atomicAdd(&h[(p0 >> 16) & 255], 1);
            if (v1) atomicAdd(&h[(p1 >> 16) & 255], 1);
            if (v2) atomicAdd(&h[(p2 >> 16) & 255], 1);
            if (v3) atomicAdd(&h[(p3 >> 16) & 255], 1);
        }
        __syncthreads();
        int v = h[t];
        cur[t] = v;
        __syncthreads();
        #pragma unroll
        for (int off = 1; off < 256; off <<= 1) {
            int add = (t >= off) ? cur[t - off] : 0;
            __syncthreads();
            cur[t] += add;
            __syncthreads();
        }
        int start = r0 + cur[t] - v;
        int node = (bid << 8) + t;
        if (node < NNODES) rowstart[node] = start;
        cur[t] = start;
        __syncthreads();
        for (int i = r0 + t; i < r1; i += 1024) {
            unsigned p0 = pairs[i];
            bool v1 = (i + 256 < r1), v2 = (i + 512 < r1), v3 = (i + 768 < r1);
            unsigned p1 = v1 ? pairs[i + 256] : 0u;
            unsigned p2 = v2 ? pairs[i + 512] : 0u;
            unsigned p3 = v3 ? pairs[i + 768] : 0u;
            int q0 = atomicAdd(&cur[(p0 >> 16) & 255], 1);
            csr_src[q0] = (unsigned short)(p0 & 0xFFFFu);
            if (v1) { int q = atomicAdd(&cur[(p1 >> 16) & 255], 1); csr_src[q] = (unsigned short)(p1 & 0xFFFFu); }
            if (v2) { int q = atomicAdd(&cur[(p2 >> 16) & 255], 1); csr_src[q] = (unsigned short)(p2 & 0xFFFFu); }
            if (v3) { int q = atomicAdd(&cur[(p3 >> 16) & 255], 1); csr_src[q] = (unsigned short)(p3 & 0xFFFFu); }
        }
    }
}

// ---------------- layer-1 GEMM: f32 A cast in-stage, 2 n-slices/block ----------
// 40KB LDS -> 4 blocks/CU. Round-5 lesson: 72KB single-pass = occupancy cliff.
__global__ __launch_bounds__(256) void k_gemm_x1(
    const float* __restrict__ X,
    const __hip_bfloat16* __restrict__ WTl,
    const __hip_bfloat16* __restrict__ WTr,
    __hip_bfloat16* __restrict__ Cl,
    __hip_bfloat16* __restrict__ Cr, int M)
{
    __shared__ short As[64 * 64];
    __shared__ short Bls[2][64 * 64];
    __shared__ short Brs[2][64 * 64];
    const int t = threadIdx.x;
    const int m0 = blockIdx.x * 64;
    const int nb = blockIdx.y * 128;     // n-slice base
    const int wave = t >> 6, lane = t & 63;
    const int wm = wave & 1, wn = wave >> 1;
    const int l15 = lane & 15, quad = lane >> 4;

    f32x4 accl[2][2][2] = {};
    f32x4 accr[2][2][2] = {};
    for (int k0 = 0; k0 < 256; k0 += 64) {
        __syncthreads();
        #pragma unroll
        for (int it = 0; it < 2; ++it) {
            int f = t + 256 * it;
            int r = f >> 3, c8 = f & 7;
            int row = m0 + r;
            uint4 v = make_uint4(0u, 0u, 0u, 0u);
            if (row < M) {
                const float4* src = reinterpret_cast<const float4*>(
                    X + (size_t)row * 256 + k0 + c8 * 8);
                float4 a = src[0], b = src[1];
                v.x = pack_bf2(a.x, a.y);
                v.y = pack_bf2(a.z, a.w);
                v.z = pack_bf2(b.x, b.y);
                v.w = pack_bf2(b.z, b.w);
            }
            *reinterpret_cast<uint4*>(&As[sw(r, c8)]) = v;
        }
        #pragma unroll
        for (int it = 0; it < 4; ++it) {
            int f = t + 256 * it;                 // 0..1023
            int s = f >> 9, ws = f & 511;
            int n = ws >> 3, c8 = ws & 7;
            int ng = nb + s * 64 + n;
            *reinterpret_cast<uint4*>(&Bls[s][sw(n, c8)]) =
                *reinterpret_cast<const uint4*>(&WTl[(size_t)ng * 256 + k0 + c8 * 8]);
            *reinterpret_cast<uint4*>(&Brs[s][sw(n, c8)]) =
                *reinterpret_cast<const uint4*>(&WTr[(size_t)ng * 256 + k0 + c8 * 8]);
        }
        __syncthreads();
        #pragma unroll
        for (int kk8 = 0; kk8 < 8; kk8 += 4) {
            bf16x8 af[2];
            #pragma unroll
            for (int mi = 0; mi < 2; ++mi)
                af[mi] = *reinterpret_cast<const bf16x8*>(
                    &As[sw(wm * 32 + mi * 16 + l15, kk8 + quad)]);
            #pragma unroll
            for (int s = 0; s < 2; ++s) {
                bf16x8 bl[2], br[2];
                #pragma unroll
                for (int ni = 0; ni < 2; ++ni) {
                    int rB = wn * 32 + ni * 16 + l15;
                    bl[ni] = *reinterpret_cast<const bf16x8*>(&Bls[s][sw(rB, kk8 + quad)]);
                    br[ni] = *reinterpret_cast<const bf16x8*>(&Brs[s][sw(rB, kk8 + quad)]);
                }
                #pragma unroll
                for (int mi = 0; mi < 2; ++mi)
                    #pragma unroll
                    for (int ni = 0; ni < 2; ++ni) {
                        accl[s][mi][ni] = __builtin_amdgcn_mfma_f32_16x16x32_bf16(
                            af[mi], bl[ni], accl[s][mi][ni], 0, 0, 0);
                        accr[s][mi][ni] = __builtin_amdgcn_mfma_f32_16x16x32_bf16(
                            af[mi], br[ni], accr[s][mi][ni], 0, 0, 0);
                    }
            }
        }
    }
    #pragma unroll
    for (int s = 0; s < 2; ++s)
        #pragma unroll
        for (int mi = 0; mi < 2; ++mi)
            #pragma unroll
            for (int ni = 0; ni < 2; ++ni)
                #pragma unroll
                for (int r = 0; r < 4; ++r) {
                    int row = m0 + wm * 32 + mi * 16 + quad * 4 + r;
                    int col = nb + s * 64 + wn * 32 + ni * 16 + l15;
                    if (row < M) {
                        Cl[(size_t)row * 256 + col] = __float2bfloat16(accl[s][mi][ni][r]);
                        Cr[(size_t)row * 256 + col] = __float2bfloat16(accr[s][mi][ni][r]);
                    }
                }
}

// ---------------- layer-2 GEMM (bf16 A, N=64) -----------------------------------
__global__ __launch_bounds__(256) void k_gemm_dual(
    const __hip_bfloat16* __restrict__ A,
    const __hip_bfloat16* __restrict__ WTl,
    const __hip_bfloat16* __restrict__ WTr,
    __hip_bfloat16* __restrict__ Cl,
    __hip_bfloat16* __restrict__ Cr, int M)
{
    __shared__ short As[64 * 64];
    __shared__ short Bls[64 * 64];
    __shared__ short Brs[64 * 64];
    const int t = threadIdx.x;
    const int m0 = blockIdx.x * 64;
    const int wave = t >> 6, lane = t & 63;
    const int wm = wave & 1, wn = wave >> 1;
    const int l15 = lane & 15, quad = lane >> 4;

    f32x4 accl[2][2] = {};
    f32x4 accr[2][2] = {};
    {
        #pragma unroll
        for (int it = 0; it < 2; ++it) {
            int f = t + 256 * it;
            int r = f >> 3, c8 = f & 7;
            int row = m0 + r;
            uint4 v = make_uint4(0u, 0u, 0u, 0u);
            if (row < M) v = *reinterpret_cast<const uint4*>(&A[(size_t)row * 64 + c8 * 8]);
            *reinterpret_cast<uint4*>(&As[sw(r, c8)]) = v;
        }
        #pragma unroll
        for (int it = 0; it < 2; ++it) {
            int f = t + 256 * it;
            int n = f >> 3, c8 = f & 7;
            *reinterpret_cast<uint4*>(&Bls[sw(n, c8)]) =
                *reinterpret_cast<const uint4*>(&WTl[(size_t)n * 64 + c8 * 8]);
            *reinterpret_cast<uint4*>(&Brs[sw(n, c8)]) =
                *reinterpret_cast<const uint4*>(&WTr[(size_t)n * 64 + c8 * 8]);
        }
        __syncthreads();
        #pragma unroll
        for (int kk8 = 0; kk8 < 8; kk8 += 4) {
            bf16x8 af[2], bl[2], br[2];
            #pragma unroll
            for (int mi = 0; mi < 2; ++mi)
                af[mi] = *reinterpret_cast<const bf16x8*>(
                    &As[sw(wm * 32 + mi * 16 + l15, kk8 + quad)]);
            #pragma unroll
            for (int ni = 0; ni < 2; ++ni) {
                int rB = wn * 32 + ni * 16 + l15;
                bl[ni] = *reinterpret_cast<const bf16x8*>(&Bls[sw(rB, kk8 + quad)]);
                br[ni] = *reinterpret_cast<const bf16x8*>(&Brs[sw(rB, kk8 + quad)]);
            }
            #pragma unroll
            for (int mi = 0; mi < 2; ++mi)
                #pragma unroll
                for (int ni = 0; ni < 2; ++ni) {
                    accl[mi][ni] = __builtin_amdgcn_mfma_f32_16x16x32_bf16(
                        af[mi], bl[ni], accl[mi][ni], 0, 0, 0);
                    accr[mi][ni] = __builtin_amdgcn_mfma_f32_16x16x32_bf16(
                        af[mi], br[ni], accr[mi][ni], 0, 0, 0);
                }
        }
    }
    #pragma unroll
    for (int mi = 0; mi < 2; ++mi)
        #pragma unroll
        for (int ni = 0; ni < 2; ++ni)
            #pragma unroll
            for (int r = 0; r < 4; ++r) {
                int row = m0 + wm * 32 + mi * 16 + quad * 4 + r;
                int col = wn * 32 + ni * 16 + l15;
                if (row < M) {
                    Cl[(size_t)row * 64 + col] = __float2bfloat16(accl[mi][ni][r]);
                    Cr[(size_t)row * 64 + col] = __float2bfloat16(accr[mi][ni][r]);
                }
            }
}

// ---------------- layer 1: one node per 64-thread wave (R4-exact: 4 edges in
// flight, uint2 8B/lane, VGPR 32, 73% occ — the measured-best operating point;
// R8 lesson: 8-deep grew the in-flight gather set -> FETCH +22MB -> slower) ----
__global__ void __launch_bounds__(64) k_node1(
                        const __hip_bfloat16* __restrict__ xl,
                        const __hip_bfloat16* __restrict__ xr,
                        const int* __restrict__ rowstart,
                        const unsigned short* __restrict__ csr_src,
                        const float* __restrict__ att,   // [4,64]
                        const float* __restrict__ bias,  // [64]
                        const float* __restrict__ lng,
                        const float* __restrict__ lnb,
                        __hip_bfloat16* __restrict__ h1b) {
    const int i = blockIdx.x;
    const int lane = threadIdx.x;
    const int grp = lane >> 4;
    const int c0 = (lane & 15) * 4;
    const int fb = lane * 4;

    uint2 rraw = *reinterpret_cast<const uint2*>(xr + (size_t)i * 256 + fb);
    v2f xr01 = bf2_to_f2(rraw.x), xr23 = bf2_to_f2(rraw.y);
    const float4 av = *reinterpret_cast<const float4*>(att + fb);
    v2f a01 = {av.x, av.y}, a23 = {av.z, av.w};

    v2f Lab = {0.f, 0.f}, Lcd = {0.f, 0.f};
    v2f Aa01 = {0.f, 0.f}, Aa23 = {0.f, 0.f};
    v2f Ab01 = {0.f, 0.f}, Ab23 = {0.f, 0.f};

    const int p0 = rowstart[i], p1 = rowstart[i + 1];
    for (int p = p0; p < p1; p += 4) {
        int j0 = csr_src[p];
        int j1 = csr_src[p + 1];   // pad-safe
        int j2 = csr_src[p + 2];
        int j3 = csr_src[p + 3];
        uint2 g0 = *reinterpret_cast<const uint2*>(xl + (size_t)j0 * 256 + fb);
        uint2 g1 = *reinterpret_cast<const uint2*>(xl + (size_t)j1 * 256 + fb);
        uint2 g2 = *reinterpret_cast<const uint2*>(xl + (size_t)j2 * 256 + fb);
        uint2 g3 = *reinterpret_cast<const uint2*>(xl + (size_t)j3 * 256 + fb);
        v2f x001 = bf2_to_f2(g0.x), x023 = bf2_to_f2(g0.y);
        v2f x101 = bf2_to_f2(g1.x), x123 = bf2_to_f2(g1.y);
        v2f x201 = bf2_to_f2(g2.x), x223 = bf2_to_f2(g2.y);
        v2f x301 = bf2_to_f2(g3.x), x323 = bf2_to_f2(g3.y);
        float e0 = red16(edot2(x001, x023, xr01, xr23, a01, a23));
        float e1 = red16(edot2(x101, x123, xr01, xr23, a01, a23));
        float e2 = red16(edot2(x201, x223, xr01, xr23, a01, a23));
        float e3 = red16(edot2(x301, x323, xr01, xr23, a01, a23));
        float pe0 = __expf(fminf(e0, 60.f));
        float pe1 = (p + 1 < p1) ? __expf(fminf(e1, 60.f)) : 0.f;
        float pe2 = (p + 2 < p1) ? __expf(fminf(e2, 60.f)) : 0.f;
        float pe3 = (p + 3 < p1) ? __expf(fminf(e3, 60.f)) : 0.f;
        Lab += (v2f){pe0, pe1};
        Lcd += (v2f){pe2, pe3};
        Aa01 += x001 * pe0; Aa23 += x023 * pe0;
        Ab01 += x101 * pe1; Ab23 += x123 * pe1;
        Aa01 += x201 * pe2; Aa23 += x223 * pe2;
        Ab01 += x301 * pe3; Ab23 += x323 * pe3;
    }
    float l = (Lab.x + Lab.y) + (Lcd.x + Lcd.y);
    float inv = 1.f / (l + SM_EPS);
    v2f V01 = (Aa01 + Ab01) * inv;
    v2f V23 = (Aa23 + Ab23) * inv;
    float v0 = V01.x, v1 = V01.y, v2 = V23.x, v3 = V23.y;
    v0 += __shfl_xor(v0, 16); v0 += __shfl_xor(v0, 32);
    v1 += __shfl_xor(v1, 16); v1 += __shfl_xor(v1, 32);
    v2 += __shfl_xor(v2, 16); v2 += __shfl_xor(v2, 32);
    v3 += __shfl_xor(v3, 16); v3 += __shfl_xor(v3, 32);
    const float4 bv = *reinterpret_cast<const float4*>(bias + c0);
    float o0 = v0 * 0.25f + bv.x;
    float o1 = v1 * 0.25f + bv.y;
    float o2 = v2 * 0.25f + bv.z;
    float o3 = v3 * 0.25f + bv.w;
    float mu = red16(o0 + o1 + o2 + o3) * 0.015625f;
    float d0 = o0 - mu, d1 = o1 - mu, d2 = o2 - mu, d3 = o3 - mu;
    float ss = red16(d0 * d0 + d1 * d1 + d2 * d2 + d3 * d3);
    float istd = rsqrtf(ss * 0.015625f + LN_EPS);
    const float4 gv = *reinterpret_cast<const float4*>(lng + c0);
    const float4 bb = *reinterpret_cast<const float4*>(lnb + c0);
    float h0 = fmaxf(d0 * istd * gv.x + bb.x, 0.f);
    float h1 = fmaxf(d1 * istd * gv.y + bb.y, 0.f);
    float h2 = fmaxf(d2 * istd * gv.z + bb.z, 0.f);
    float h3 = fmaxf(d3 * istd * gv.w + bb.w, 0.f);
    if (grp == 0) {
        uint2 pk;
        pk.x = pack_bf2(h0, h1);
        pk.y = pack_bf2(h2, h3);
        *reinterpret_cast<uint2*>(h1b + (size_t)i * 64 + c0) = pk;
    }
}

// ---------------- layer 2: one node per 64-thread wave (R4 structure) ----------
__global__ void __launch_bounds__(64) k_node2(
                        const __hip_bfloat16* __restrict__ xl,
                        const __hip_bfloat16* __restrict__ xr,
                        const int* __restrict__ rowstart,
                        const unsigned short* __restrict__ csr_src,
                        const float* __restrict__ att,   // [64]
                        const float* __restrict__ bias,
                        const float* __restrict__ lng,
                        const float* __restrict__ lnb,
                        float* __restrict__ out) {
    const int i = blockIdx.x;
    const int lane = threadIdx.x;
    const int grp = lane >> 4;
    const int c0 = (lane & 15) * 4;

    uint2 rraw = *reinterpret_cast<const uint2*>(xr + (size_t)i * 64 + c0);
    v2f xr01 = bf2_to_f2(rraw.x), xr23 = bf2_to_f2(rraw.y);
    const float4 avf = *reinterpret_cast<const float4*>(att + c0);
    v2f a01 = {avf.x, avf.y}, a23 = {avf.z, avf.w};
    float l = 0.f;
    v2f A01 = {0.f, 0.f}, A23 = {0.f, 0.f};

    const char* rowbase = (const char*)xl + c0 * 2;
    const int p0 = rowstart[i], p1 = rowstart[i + 1];
    for (int p = p0; p < p1; p += 4) {
        int pe = p + grp;
        int j = csr_src[pe];                          // pad-safe
        uint2 g = *reinterpret_cast<const uint2*>(rowbase + ((size_t)j << 7));
        v2f x01 = bf2_to_f2(g.x), x23 = bf2_to_f2(g.y);
        float e = red16(edot2(x01, x23, xr01, xr23, a01, a23));
        float w = (pe < p1) ? __expf(fminf(e, 60.f)) : 0.f;
        l += w;
        A01 += x01 * w;
        A23 += x23 * w;
    }
    #pragma unroll
    for (int s = 16; s <= 32; s <<= 1) {
        l     += __shfl_xor(l, s);
        A01.x += __shfl_xor(A01.x, s);
        A01.y += __shfl_xor(A01.y, s);
        A23.x += __shfl_xor(A23.x, s);
        A23.y += __shfl_xor(A23.y, s);
    }
    float inv = 1.f / (l + SM_EPS);
    const float4 bv = *reinterpret_cast<const float4*>(bias + c0);
    float o0 = A01.x * inv + bv.x;
    float o1 = A01.y * inv + bv.y;
    float o2 = A23.x * inv + bv.z;
    float o3 = A23.y * inv + bv.w;
    float mu = red16(o0 + o1 + o2 + o3) * 0.015625f;
    float d0 = o0 - mu, d1 = o1 - mu, d2 = o2 - mu, d3 = o3 - mu;
    float ss = red16(d0 * d0 + d1 * d1 + d2 * d2 + d3 * d3);
    float istd = rsqrtf(ss * 0.015625f + LN_EPS);
    const float4 gv = *reinterpret_cast<const float4*>(lng + c0);
    const float4 bb = *reinterpret_cast<const float4*>(lnb + c0);
    if (grp == 0) {
        float4 y;
        y.x = d0 * istd * gv.x + bb.x;
        y.y = d1 * istd * gv.y + bb.y;
        y.z = d2 * istd * gv.z + bb.z;
        y.w = d3 * istd * gv.w + bb.w;
        *reinterpret_cast<float4*>(out + (size_t)i * 64 + c0) = y;
    }
}

extern "C" void kernel_launch(void* const* d_in, const int* in_sizes, int n_in,
                              void* d_out, int out_size, void* d_ws, size_t ws_size,
                              hipStream_t stream) {
    const float* x    = (const float*)d_in[0];
    const int*   ei   = (const int*)d_in[1];
    const float* W1l  = (const float*)d_in[2];
    const float* W1r  = (const float*)d_in[3];
    const float* att1 = (const float*)d_in[4];
    const float* b1   = (const float*)d_in[5];
    const float* ln1g = (const float*)d_in[6];
    const float* ln1b = (const float*)d_in[7];
    const float* W2l  = (const float*)d_in[8];
    const float* W2r  = (const float*)d_in[9];
    const float* att2 = (const float*)d_in[10];
    const float* b2   = (const float*)d_in[11];
    const float* ln2g = (const float*)d_in[12];
    const float* ln2b = (const float*)d_in[13];
    float* out = (float*)d_out;

    char* w = (char*)d_ws;
    size_t off = 0;
    auto alloc = [&](size_t bytes) -> void* {
        void* p = w + off;
        off += (bytes + 255) & ~(size_t)255;
        return p;
    };
    __hip_bfloat16* xl1  = (__hip_bfloat16*)alloc((size_t)NNODES * 256 * 2);
    __hip_bfloat16* xr1  = (__hip_bfloat16*)alloc((size_t)NNODES * 256 * 2);
    __hip_bfloat16* h1b  = (__hip_bfloat16*)alloc((size_t)NNODES * 64 * 2);
    __hip_bfloat16* xl2  = (__hip_bfloat16*)alloc((size_t)NNODES * 64 * 2);
    __hip_bfloat16* xr2  = (__hip_bfloat16*)alloc((size_t)NNODES * 64 * 2);
    __hip_bfloat16* w1lT = (__hip_bfloat16*)alloc(256 * 256 * 2);
    __hip_bfloat16* w1rT = (__hip_bfloat16*)alloc(256 * 256 * 2);
    __hip_bfloat16* w2lT = (__hip_bfloat16*)alloc(64 * 64 * 2);
    __hip_bfloat16* w2rT = (__hip_bfloat16*)alloc(64 * 64 * 2);
    int* part     = (int*)alloc((size_t)256 * NBLK * 4);       // per-(bucket,block)
    unsigned* pairs = (unsigned*)alloc((size_t)ETOT * 4);
    int* rowstart = (int*)alloc((size_t)(NNODES + 1) * 4);
    unsigned short* csr_src = (unsigned short*)alloc((size_t)(ETOT + 16) * 2);
    int* blocksum = (int*)alloc(1024);
    (void)ws_size; (void)in_sizes; (void)n_in; (void)out_size;

    // ---- whole CSR build + weight cast: ONE cooperative kernel (5 grid syncs)
    {
        void* cargs[] = {
            (void*)&W1l, (void*)&W1r, (void*)&W2l, (void*)&W2r,
            (void*)&w1lT, (void*)&w1rT, (void*)&w2lT, (void*)&w2rT,
            (void*)&csr_src, (void*)&rowstart, (void*)&ei, (void*)&part,
            (void*)&pairs, (void*)&blocksum
        };
        hipLaunchCooperativeKernel((const void*)k_csr_coop,
                                   dim3(COOPB), dim3(256), cargs, 0, stream);
    }

    // ---- dense pipeline
    const int gm = (NNODES + 63) / 64;                  // 782
    dim3 g1(gm, 2);
    k_gemm_x1<<<g1, 256, 0, stream>>>(x, w1lT, w1rT, xl1, xr1, NNODES);
    k_node1<<<NNODES, 64, 0, stream>>>(xl1, xr1, rowstart, csr_src,
                                       att1, b1, ln1g, ln1b, h1b);
    k_gemm_dual<<<gm, 256, 0, stream>>>(h1b, w2lT, w2rT, xl2, xr2, NNODES);
    k_node2<<<NNODES, 64, 0, stream>>>(xl2, xr2, rowstart, csr_src,
                                       att2, b2, ln2g, ln2b, out);
}

// Round 10
// 293.352 us; speedup vs baseline: 1.5329x; 1.5329x over previous
//
#include <hip/hip_runtime.h>
#include <hip/hip_bf16.h>

#define NNODES 50000
#define NEDGES 800000
#define ETOT   850000
#define NEG_SLOPE 0.2f
#define LN_EPS 1e-5f
#define SM_EPS 1e-16f
#define NBUCK 196                 // ceil(50000/256) buckets of 256 nodes
#define NBLK 208                  // ceil(850000/4096) edge chunks
#define CHUNK 4096
#define CASTB 544                 // cast blocks inside k_prep

typedef short bf16x8 __attribute__((ext_vector_type(8)));
typedef float f32x4  __attribute__((ext_vector_type(4)));
typedef float v2f    __attribute__((ext_vector_type(2)));

__device__ __forceinline__ unsigned pack_bf2(float a, float b) {
    __hip_bfloat162 p;
    p.x = __float2bfloat16(a);
    p.y = __float2bfloat16(b);
    return *reinterpret_cast<unsigned*>(&p);
}

__device__ __forceinline__ v2f bf2_to_f2(unsigned u) {
    v2f r;
    r.x = __int_as_float((int)(u << 16));
    r.y = __int_as_float((int)(u & 0xFFFF0000u));
    return r;
}

template <int CTRL>
__device__ __forceinline__ float dpp_add(float x) {
    return x + __int_as_float(__builtin_amdgcn_update_dpp(
        0, __float_as_int(x), CTRL, 0xF, 0xF, true));
}
__device__ __forceinline__ float red16(float x) {
    x = dpp_add<0xB1>(x);
    x = dpp_add<0x4E>(x);
    x = dpp_add<0x124>(x);
    x = dpp_add<0x128>(x);
    return x;
}

__device__ __forceinline__ float edot2(v2f x01, v2f x23, v2f xr01, v2f xr23,
                                       v2f a01, v2f a23) {
    v2f s01 = x01 + xr01;
    v2f s23 = x23 + xr23;
    v2f t01 = __builtin_elementwise_max(s01, s01 * NEG_SLOPE);
    v2f t23 = __builtin_elementwise_max(s23, s23 * NEG_SLOPE);
    v2f d = t01 * a01 + t23 * a23;
    return d.x + d.y;
}

// XOR-swizzled LDS offset for 64-col short tiles (16B granules)
__device__ __forceinline__ int sw(int row, int c8) {
    return (row << 6) + ((c8 ^ (row & 7)) << 3);
}

// ---------------- merged prep: weights cast (blocks 0..543) + bucket hist -------
// R9 lesson: do NOT fuse the CSR phases behind grid.sync() — cooperative launch
// pinned occupancy at 1 block/CU and each sync cost ~30us (178us total vs ~50us
// as separate launches). Launch boundaries are cheaper than grid-wide sync here.
__global__ void __launch_bounds__(256) k_prep(
        const float* __restrict__ W1l, const float* __restrict__ W1r,
        const float* __restrict__ W2l, const float* __restrict__ W2r,
        __hip_bfloat16* __restrict__ w1lT, __hip_bfloat16* __restrict__ w1rT,
        __hip_bfloat16* __restrict__ w2lT, __hip_bfloat16* __restrict__ w2rT,
        unsigned short* __restrict__ csr_src, int* __restrict__ rowstart,
        const int* __restrict__ ei, int* __restrict__ part) {
    __shared__ int h[256];
    if (blockIdx.x < CASTB) {
        int t = blockIdx.x * 256 + threadIdx.x;
        if (t < 16) csr_src[ETOT + t] = 0;       // pad: node-0 reads, weight-masked
        if (t == 16) rowstart[NNODES] = ETOT;    // sentinel
        if (t < 65536) {
            int k = t >> 8, n = t & 255;
            w1lT[n * 256 + k] = __float2bfloat16(W1l[t]);
        } else if (t < 131072) {
            int u = t - 65536; int k = u >> 8, n = u & 255;
            w1rT[n * 256 + k] = __float2bfloat16(W1r[u]);
        } else if (t < 135168) {
            int u = t - 131072; int k = u >> 6, n = u & 63;
            w2lT[n * 64 + k] = __float2bfloat16(W2l[u]);
        } else if (t < 139264) {
            int u = t - 135168; int k = u >> 6, n = u & 63;
            w2rT[n * 64 + k] = __float2bfloat16(W2r[u]);
        }
        return;
    }
    // bucket histogram: LDS only, per-(bucket,chunk) counts
    const int b = blockIdx.x - CASTB;
    h[threadIdx.x] = 0;
    __syncthreads();
    const int base = b * CHUNK;
    #pragma unroll
    for (int it = 0; it < 16; ++it) {
        int e = base + it * 256 + threadIdx.x;
        if (e < ETOT) {
            int dst = (e < NEDGES) ? ei[NEDGES + e] : (e - NEDGES);
            atomicAdd(&h[dst >> 8], 1);
        }
    }
    __syncthreads();
    part[threadIdx.x * NBLK + b] = h[threadIdx.x];   // bucket-major
}

// ---------------- single-block full scan of part (53248 = 256 rows x 208) ------
// Thread t owns bucket-row t: serial row-sum (L2-hot), block exclusive scan of
// row totals, then rewrite row with running prefix. Replaces 3 scan launches.
__global__ void __launch_bounds__(256) k_scan_one(int* __restrict__ part) {
    __shared__ int s[256];
    const int t = threadIdx.x;
    const int base = t * NBLK;
    int sum = 0;
    for (int c = 0; c < NBLK; ++c) sum += part[base + c];
    s[t] = sum;
    __syncthreads();
    #pragma unroll
    for (int off = 1; off < 256; off <<= 1) {
        int add = (t >= off) ? s[t - off] : 0;
        __syncthreads();
        s[t] += add;
        __syncthreads();
    }
    int running = s[t] - sum;              // exclusive prefix of row t
    for (int c = 0; c < NBLK; ++c) {
        int tmp = part[base + c];
        part[base + c] = running;
        running += tmp;
    }
}

// ---------------- bucket scatter: LDS cursors, coalesced-run pair writes --------
__global__ void __launch_bounds__(256) k_bscatter(const int* __restrict__ ei,
                                                  const int* __restrict__ partoff,
                                                  unsigned* __restrict__ pairs) {
    __shared__ int cnt[256];
    const int t = threadIdx.x;
    cnt[t] = partoff[t * NBLK + blockIdx.x];
    __syncthreads();
    const int base = blockIdx.x * CHUNK;
    #pragma unroll
    for (int it = 0; it < 16; ++it) {
        int e = base + it * 256 + t;
        if (e < ETOT) {
            int dst, src;
            if (e < NEDGES) { dst = ei[NEDGES + e]; src = ei[e]; }
            else            { dst = e - NEDGES;     src = dst; }
            int pos = atomicAdd(&cnt[dst >> 8], 1);
            pairs[pos] = ((unsigned)dst << 16) | (unsigned)src;
        }
    }
}

// ---------------- fused per-bucket: count + LDS scan + rowstart + scatter -------
__global__ void __launch_bounds__(256) k_nfinal(const unsigned* __restrict__ pairs,
                                                const int* __restrict__ partoff,
                                                int* __restrict__ rowstart,
                                                unsigned short* __restrict__ csr_src) {
    __shared__ int h[256];
    __shared__ int cur[256];
    const int b = blockIdx.x;
    const int t = threadIdx.x;
    const int r0 = partoff[b * NBLK];
    const int r1 = partoff[(b + 1) * NBLK];
    h[t] = 0;
    __syncthreads();
    for (int i = r0 + t; i < r1; i += 1024) {
        unsigned p0 = pairs[i];
        bool v1 = (i + 256 < r1), v2 = (i + 512 < r1), v3 = (i + 768 < r1);
        unsigned p1 = v1 ? pairs[i + 256] : 0u;
        unsigned p2 = v2 ? pairs[i + 512] : 0u;
        unsigned p3 = v3 ? pairs[i + 768] : 0u;
        atomicAdd(&h[(p0 >> 16) & 255], 1);
        if (v1) atomicAdd(&h[(p1 >> 16) & 255], 1);
        if (v2) atomicAdd(&h[(p2 >> 16) & 255], 1);
        if (v3) atomicAdd(&h[(p3 >> 16) & 255], 1);
    }
    __syncthreads();
    int v = h[t];
    cur[t] = v;
    __syncthreads();
    #pragma unroll
    for (int off = 1; off < 256; off <<= 1) {
        int add = (t >= off) ? cur[t - off] : 0;
        __syncthreads();
        cur[t] += add;
        __syncthreads();
    }
    int start = r0 + cur[t] - v;
    int node = (b << 8) + t;
    if (node < NNODES) rowstart[node] = start;
    cur[t] = start;
    __syncthreads();
    for (int i = r0 + t; i < r1; i += 1024) {
        unsigned p0 = pairs[i];
        bool v1 = (i + 256 < r1), v2 = (i + 512 < r1), v3 = (i + 768 < r1);
        unsigned p1 = v1 ? pairs[i + 256] : 0u;
        unsigned p2 = v2 ? pairs[i + 512] : 0u;
        unsigned p3 = v3 ? pairs[i + 768] : 0u;
        int q0 = atomicAdd(&cur[(p0 >> 16) & 255], 1);
        csr_src[q0] = (unsigned short)(p0 & 0xFFFFu);
        if (v1) { int q = atomicAdd(&cur[(p1 >> 16) & 255], 1); csr_src[q] = (unsigned short)(p1 & 0xFFFFu); }
        if (v2) { int q = atomicAdd(&cur[(p2 >> 16) & 255], 1); csr_src[q] = (unsigned short)(p2 & 0xFFFFu); }
        if (v3) { int q = atomicAdd(&cur[(p3 >> 16) & 255], 1); csr_src[q] = (unsigned short)(p3 & 0xFFFFu); }
    }
}

// ---------------- layer-1 GEMM: f32 A cast in-stage, 2 n-slices/block ----------
// 40KB LDS -> 4 blocks/CU. Round-5 lesson: 72KB single-pass = occupancy cliff.
__global__ __launch_bounds__(256) void k_gemm_x1(
    const float* __restrict__ X,
    const __hip_bfloat16* __restrict__ WTl,
    const __hip_bfloat16* __restrict__ WTr,
    __hip_bfloat16* __restrict__ Cl,
    __hip_bfloat16* __restrict__ Cr, int M)
{
    __shared__ short As[64 * 64];
    __shared__ short Bls[2][64 * 64];
    __shared__ short Brs[2][64 * 64];
    const int t = threadIdx.x;
    const int m0 = blockIdx.x * 64;
    const int nb = blockIdx.y * 128;     // n-slice base
    const int wave = t >> 6, lane = t & 63;
    const int wm = wave & 1, wn = wave >> 1;
    const int l15 = lane & 15, quad = lane >> 4;

    f32x4 accl[2][2][2] = {};
    f32x4 accr[2][2][2] = {};
    for (int k0 = 0; k0 < 256; k0 += 64) {
        __syncthreads();
        #pragma unroll
        for (int it = 0; it < 2; ++it) {
            int f = t + 256 * it;
            int r = f >> 3, c8 = f & 7;
            int row = m0 + r;
            uint4 v = make_uint4(0u, 0u, 0u, 0u);
            if (row < M) {
                const float4* src = reinterpret_cast<const float4*>(
                    X + (size_t)row * 256 + k0 + c8 * 8);
                float4 a = src[0], b = src[1];
                v.x = pack_bf2(a.x, a.y);
                v.y = pack_bf2(a.z, a.w);
                v.z = pack_bf2(b.x, b.y);
                v.w = pack_bf2(b.z, b.w);
            }
            *reinterpret_cast<uint4*>(&As[sw(r, c8)]) = v;
        }
        #pragma unroll
        for (int it = 0; it < 4; ++it) {
            int f = t + 256 * it;                 // 0..1023
            int s = f >> 9, ws = f & 511;
            int n = ws >> 3, c8 = ws & 7;
            int ng = nb + s * 64 + n;
            *reinterpret_cast<uint4*>(&Bls[s][sw(n, c8)]) =
                *reinterpret_cast<const uint4*>(&WTl[(size_t)ng * 256 + k0 + c8 * 8]);
            *reinterpret_cast<uint4*>(&Brs[s][sw(n, c8)]) =
                *reinterpret_cast<const uint4*>(&WTr[(size_t)ng * 256 + k0 + c8 * 8]);
        }
        __syncthreads();
        #pragma unroll
        for (int kk8 = 0; kk8 < 8; kk8 += 4) {
            bf16x8 af[2];
            #pragma unroll
            for (int mi = 0; mi < 2; ++mi)
                af[mi] = *reinterpret_cast<const bf16x8*>(
                    &As[sw(wm * 32 + mi * 16 + l15, kk8 + quad)]);
            #pragma unroll
            for (int s = 0; s < 2; ++s) {
                bf16x8 bl[2], br[2];
                #pragma unroll
                for (int ni = 0; ni < 2; ++ni) {
                    int rB = wn * 32 + ni * 16 + l15;
                    bl[ni] = *reinterpret_cast<const bf16x8*>(&Bls[s][sw(rB, kk8 + quad)]);
                    br[ni] = *reinterpret_cast<const bf16x8*>(&Brs[s][sw(rB, kk8 + quad)]);
                }
                #pragma unroll
                for (int mi = 0; mi < 2; ++mi)
                    #pragma unroll
                    for (int ni = 0; ni < 2; ++ni) {
                        accl[s][mi][ni] = __builtin_amdgcn_mfma_f32_16x16x32_bf16(
                            af[mi], bl[ni], accl[s][mi][ni], 0, 0, 0);
                        accr[s][mi][ni] = __builtin_amdgcn_mfma_f32_16x16x32_bf16(
                            af[mi], br[ni], accr[s][mi][ni], 0, 0, 0);
                    }
            }
        }
    }
    #pragma unroll
    for (int s = 0; s < 2; ++s)
        #pragma unroll
        for (int mi = 0; mi < 2; ++mi)
            #pragma unroll
            for (int ni = 0; ni < 2; ++ni)
                #pragma unroll
                for (int r = 0; r < 4; ++r) {
                    int row = m0 + wm * 32 + mi * 16 + quad * 4 + r;
                    int col = nb + s * 64 + wn * 32 + ni * 16 + l15;
                    if (row < M) {
                        Cl[(size_t)row * 256 + col] = __float2bfloat16(accl[s][mi][ni][r]);
                        Cr[(size_t)row * 256 + col] = __float2bfloat16(accr[s][mi][ni][r]);
                    }
                }
}

// ---------------- layer-2 GEMM (bf16 A, N=64) -----------------------------------
__global__ __launch_bounds__(256) void k_gemm_dual(
    const __hip_bfloat16* __restrict__ A,
    const __hip_bfloat16* __restrict__ WTl,
    const __hip_bfloat16* __restrict__ WTr,
    __hip_bfloat16* __restrict__ Cl,
    __hip_bfloat16* __restrict__ Cr, int M)
{
    __shared__ short As[64 * 64];
    __shared__ short Bls[64 * 64];
    __shared__ short Brs[64 * 64];
    const int t = threadIdx.x;
    const int m0 = blockIdx.x * 64;
    const int wave = t >> 6, lane = t & 63;
    const int wm = wave & 1, wn = wave >> 1;
    const int l15 = lane & 15, quad = lane >> 4;

    f32x4 accl[2][2] = {};
    f32x4 accr[2][2] = {};
    {
        #pragma unroll
        for (int it = 0; it < 2; ++it) {
            int f = t + 256 * it;
            int r = f >> 3, c8 = f & 7;
            int row = m0 + r;
            uint4 v = make_uint4(0u, 0u, 0u, 0u);
            if (row < M) v = *reinterpret_cast<const uint4*>(&A[(size_t)row * 64 + c8 * 8]);
            *reinterpret_cast<uint4*>(&As[sw(r, c8)]) = v;
        }
        #pragma unroll
        for (int it = 0; it < 2; ++it) {
            int f = t + 256 * it;
            int n = f >> 3, c8 = f & 7;
            *reinterpret_cast<uint4*>(&Bls[sw(n, c8)]) =
                *reinterpret_cast<const uint4*>(&WTl[(size_t)n * 64 + c8 * 8]);
            *reinterpret_cast<uint4*>(&Brs[sw(n, c8)]) =
                *reinterpret_cast<const uint4*>(&WTr[(size_t)n * 64 + c8 * 8]);
        }
        __syncthreads();
        #pragma unroll
        for (int kk8 = 0; kk8 < 8; kk8 += 4) {
            bf16x8 af[2], bl[2], br[2];
            #pragma unroll
            for (int mi = 0; mi < 2; ++mi)
                af[mi] = *reinterpret_cast<const bf16x8*>(
                    &As[sw(wm * 32 + mi * 16 + l15, kk8 + quad)]);
            #pragma unroll
            for (int ni = 0; ni < 2; ++ni) {
                int rB = wn * 32 + ni * 16 + l15;
                bl[ni] = *reinterpret_cast<const bf16x8*>(&Bls[sw(rB, kk8 + quad)]);
                br[ni] = *reinterpret_cast<const bf16x8*>(&Brs[sw(rB, kk8 + quad)]);
            }
            #pragma unroll
            for (int mi = 0; mi < 2; ++mi)
                #pragma unroll
                for (int ni = 0; ni < 2; ++ni) {
                    accl[mi][ni] = __builtin_amdgcn_mfma_f32_16x16x32_bf16(
                        af[mi], bl[ni], accl[mi][ni], 0, 0, 0);
                    accr[mi][ni] = __builtin_amdgcn_mfma_f32_16x16x32_bf16(
                        af[mi], br[ni], accr[mi][ni], 0, 0, 0);
                }
        }
    }
    #pragma unroll
    for (int mi = 0; mi < 2; ++mi)
        #pragma unroll
        for (int ni = 0; ni < 2; ++ni)
            #pragma unroll
            for (int r = 0; r < 4; ++r) {
                int row = m0 + wm * 32 + mi * 16 + quad * 4 + r;
                int col = wn * 32 + ni * 16 + l15;
                if (row < M) {
                    Cl[(size_t)row * 64 + col] = __float2bfloat16(accl[mi][ni][r]);
                    Cr[(size_t)row * 64 + col] = __float2bfloat16(accr[mi][ni][r]);
                }
            }
}

// ---------------- layer 1: one node per 64-thread wave (R4-exact: 4 edges in
// flight, uint2 8B/lane, VGPR 32, 73% occ — measured-best operating point.
// R8 lesson: 8-deep grew the in-flight gather set -> FETCH +22MB -> slower) ----
__global__ void __launch_bounds__(64) k_node1(
                        const __hip_bfloat16* __restrict__ xl,
                        const __hip_bfloat16* __restrict__ xr,
                        const int* __restrict__ rowstart,
                        const unsigned short* __restrict__ csr_src,
                        const float* __restrict__ att,   // [4,64]
                        const float* __restrict__ bias,  // [64]
                        const float* __restrict__ lng,
                        const float* __restrict__ lnb,
                        __hip_bfloat16* __restrict__ h1b) {
    const int i = blockIdx.x;
    const int lane = threadIdx.x;
    const int grp = lane >> 4;
    const int c0 = (lane & 15) * 4;
    const int fb = lane * 4;

    uint2 rraw = *reinterpret_cast<const uint2*>(xr + (size_t)i * 256 + fb);
    v2f xr01 = bf2_to_f2(rraw.x), xr23 = bf2_to_f2(rraw.y);
    const float4 av = *reinterpret_cast<const float4*>(att + fb);
    v2f a01 = {av.x, av.y}, a23 = {av.z, av.w};

    v2f Lab = {0.f, 0.f}, Lcd = {0.f, 0.f};
    v2f Aa01 = {0.f, 0.f}, Aa23 = {0.f, 0.f};
    v2f Ab01 = {0.f, 0.f}, Ab23 = {0.f, 0.f};

    const int p0 = rowstart[i], p1 = rowstart[i + 1];
    for (int p = p0; p < p1; p += 4) {
        int j0 = csr_src[p];
        int j1 = csr_src[p + 1];   // pad-safe
        int j2 = csr_src[p + 2];
        int j3 = csr_src[p + 3];
        uint2 g0 = *reinterpret_cast<const uint2*>(xl + (size_t)j0 * 256 + fb);
        uint2 g1 = *reinterpret_cast<const uint2*>(xl + (size_t)j1 * 256 + fb);
        uint2 g2 = *reinterpret_cast<const uint2*>(xl + (size_t)j2 * 256 + fb);
        uint2 g3 = *reinterpret_cast<const uint2*>(xl + (size_t)j3 * 256 + fb);
        v2f x001 = bf2_to_f2(g0.x), x023 = bf2_to_f2(g0.y);
        v2f x101 = bf2_to_f2(g1.x), x123 = bf2_to_f2(g1.y);
        v2f x201 = bf2_to_f2(g2.x), x223 = bf2_to_f2(g2.y);
        v2f x301 = bf2_to_f2(g3.x), x323 = bf2_to_f2(g3.y);
        float e0 = red16(edot2(x001, x023, xr01, xr23, a01, a23));
        float e1 = red16(edot2(x101, x123, xr01, xr23, a01, a23));
        float e2 = red16(edot2(x201, x223, xr01, xr23, a01, a23));
        float e3 = red16(edot2(x301, x323, xr01, xr23, a01, a23));
        float pe0 = __expf(fminf(e0, 60.f));
        float pe1 = (p + 1 < p1) ? __expf(fminf(e1, 60.f)) : 0.f;
        float pe2 = (p + 2 < p1) ? __expf(fminf(e2, 60.f)) : 0.f;
        float pe3 = (p + 3 < p1) ? __expf(fminf(e3, 60.f)) : 0.f;
        Lab += (v2f){pe0, pe1};
        Lcd += (v2f){pe2, pe3};
        Aa01 += x001 * pe0; Aa23 += x023 * pe0;
        Ab01 += x101 * pe1; Ab23 += x123 * pe1;
        Aa01 += x201 * pe2; Aa23 += x223 * pe2;
        Ab01 += x301 * pe3; Ab23 += x323 * pe3;
    }
    float l = (Lab.x + Lab.y) + (Lcd.x + Lcd.y);
    float inv = 1.f / (l + SM_EPS);
    v2f V01 = (Aa01 + Ab01) * inv;
    v2f V23 = (Aa23 + Ab23) * inv;
    float v0 = V01.x, v1 = V01.y, v2 = V23.x, v3 = V23.y;
    v0 += __shfl_xor(v0, 16); v0 += __shfl_xor(v0, 32);
    v1 += __shfl_xor(v1, 16); v1 += __shfl_xor(v1, 32);
    v2 += __shfl_xor(v2, 16); v2 += __shfl_xor(v2, 32);
    v3 += __shfl_xor(v3, 16); v3 += __shfl_xor(v3, 32);
    const float4 bv = *reinterpret_cast<const float4*>(bias + c0);
    float o0 = v0 * 0.25f + bv.x;
    float o1 = v1 * 0.25f + bv.y;
    float o2 = v2 * 0.25f + bv.z;
    float o3 = v3 * 0.25f + bv.w;
    float mu = red16(o0 + o1 + o2 + o3) * 0.015625f;
    float d0 = o0 - mu, d1 = o1 - mu, d2 = o2 - mu, d3 = o3 - mu;
    float ss = red16(d0 * d0 + d1 * d1 + d2 * d2 + d3 * d3);
    float istd = rsqrtf(ss * 0.015625f + LN_EPS);
    const float4 gv = *reinterpret_cast<const float4*>(lng + c0);
    const float4 bb = *reinterpret_cast<const float4*>(lnb + c0);
    float h0 = fmaxf(d0 * istd * gv.x + bb.x, 0.f);
    float h1 = fmaxf(d1 * istd * gv.y + bb.y, 0.f);
    float h2 = fmaxf(d2 * istd * gv.z + bb.z, 0.f);
    float h3 = fmaxf(d3 * istd * gv.w + bb.w, 0.f);
    if (grp == 0) {
        uint2 pk;
        pk.x = pack_bf2(h0, h1);
        pk.y = pack_bf2(h2, h3);
        *reinterpret_cast<uint2*>(h1b + (size_t)i * 64 + c0) = pk;
    }
}

// ---------------- layer 2: one node per 64-thread wave (R4 structure) ----------
__global__ void __launch_bounds__(64) k_node2(
                        const __hip_bfloat16* __restrict__ xl,
                        const __hip_bfloat16* __restrict__ xr,
                        const int* __restrict__ rowstart,
                        const unsigned short* __restrict__ csr_src,
                        const float* __restrict__ att,   // [64]
                        const float* __restrict__ bias,
                        const float* __restrict__ lng,
                        const float* __restrict__ lnb,
                        float* __restrict__ out) {
    const int i = blockIdx.x;
    const int lane = threadIdx.x;
    const int grp = lane >> 4;
    const int c0 = (lane & 15) * 4;

    uint2 rraw = *reinterpret_cast<const uint2*>(xr + (size_t)i * 64 + c0);
    v2f xr01 = bf2_to_f2(rraw.x), xr23 = bf2_to_f2(rraw.y);
    const float4 avf = *reinterpret_cast<const float4*>(att + c0);
    v2f a01 = {avf.x, avf.y}, a23 = {avf.z, avf.w};
    float l = 0.f;
    v2f A01 = {0.f, 0.f}, A23 = {0.f, 0.f};

    const char* rowbase = (const char*)xl + c0 * 2;
    const int p0 = rowstart[i], p1 = rowstart[i + 1];
    for (int p = p0; p < p1; p += 4) {
        int pe = p + grp;
        int j = csr_src[pe];                          // pad-safe
        uint2 g = *reinterpret_cast<const uint2*>(rowbase + ((size_t)j << 7));
        v2f x01 = bf2_to_f2(g.x), x23 = bf2_to_f2(g.y);
        float e = red16(edot2(x01, x23, xr01, xr23, a01, a23));
        float w = (pe < p1) ? __expf(fminf(e, 60.f)) : 0.f;
        l += w;
        A01 += x01 * w;
        A23 += x23 * w;
    }
    #pragma unroll
    for (int s = 16; s <= 32; s <<= 1) {
        l     += __shfl_xor(l, s);
        A01.x += __shfl_xor(A01.x, s);
        A01.y += __shfl_xor(A01.y, s);
        A23.x += __shfl_xor(A23.x, s);
        A23.y += __shfl_xor(A23.y, s);
    }
    float inv = 1.f / (l + SM_EPS);
    const float4 bv = *reinterpret_cast<const float4*>(bias + c0);
    float o0 = A01.x * inv + bv.x;
    float o1 = A01.y * inv + bv.y;
    float o2 = A23.x * inv + bv.z;
    float o3 = A23.y * inv + bv.w;
    float mu = red16(o0 + o1 + o2 + o3) * 0.015625f;
    float d0 = o0 - mu, d1 = o1 - mu, d2 = o2 - mu, d3 = o3 - mu;
    float ss = red16(d0 * d0 + d1 * d1 + d2 * d2 + d3 * d3);
    float istd = rsqrtf(ss * 0.015625f + LN_EPS);
    const float4 gv = *reinterpret_cast<const float4*>(lng + c0);
    const float4 bb = *reinterpret_cast<const float4*>(lnb + c0);
    if (grp == 0) {
        float4 y;
        y.x = d0 * istd * gv.x + bb.x;
        y.y = d1 * istd * gv.y + bb.y;
        y.z = d2 * istd * gv.z + bb.z;
        y.w = d3 * istd * gv.w + bb.w;
        *reinterpret_cast<float4*>(out + (size_t)i * 64 + c0) = y;
    }
}

extern "C" void kernel_launch(void* const* d_in, const int* in_sizes, int n_in,
                              void* d_out, int out_size, void* d_ws, size_t ws_size,
                              hipStream_t stream) {
    const float* x    = (const float*)d_in[0];
    const int*   ei   = (const int*)d_in[1];
    const float* W1l  = (const float*)d_in[2];
    const float* W1r  = (const float*)d_in[3];
    const float* att1 = (const float*)d_in[4];
    const float* b1   = (const float*)d_in[5];
    const float* ln1g = (const float*)d_in[6];
    const float* ln1b = (const float*)d_in[7];
    const float* W2l  = (const float*)d_in[8];
    const float* W2r  = (const float*)d_in[9];
    const float* att2 = (const float*)d_in[10];
    const float* b2   = (const float*)d_in[11];
    const float* ln2g = (const float*)d_in[12];
    const float* ln2b = (const float*)d_in[13];
    float* out = (float*)d_out;

    char* w = (char*)d_ws;
    size_t off = 0;
    auto alloc = [&](size_t bytes) -> void* {
        void* p = w + off;
        off += (bytes + 255) & ~(size_t)255;
        return p;
    };
    __hip_bfloat16* xl1  = (__hip_bfloat16*)alloc((size_t)NNODES * 256 * 2);
    __hip_bfloat16* xr1  = (__hip_bfloat16*)alloc((size_t)NNODES * 256 * 2);
    __hip_bfloat16* h1b  = (__hip_bfloat16*)alloc((size_t)NNODES * 64 * 2);
    __hip_bfloat16* xl2  = (__hip_bfloat16*)alloc((size_t)NNODES * 64 * 2);
    __hip_bfloat16* xr2  = (__hip_bfloat16*)alloc((size_t)NNODES * 64 * 2);
    __hip_bfloat16* w1lT = (__hip_bfloat16*)alloc(256 * 256 * 2);
    __hip_bfloat16* w1rT = (__hip_bfloat16*)alloc(256 * 256 * 2);
    __hip_bfloat16* w2lT = (__hip_bfloat16*)alloc(64 * 64 * 2);
    __hip_bfloat16* w2rT = (__hip_bfloat16*)alloc(64 * 64 * 2);
    int* part     = (int*)alloc((size_t)256 * NBLK * 4);       // per-(bucket,chunk)
    unsigned* pairs = (unsigned*)alloc((size_t)ETOT * 4);
    int* rowstart = (int*)alloc((size_t)(NNODES + 1) * 4);
    unsigned short* csr_src = (unsigned short*)alloc((size_t)(ETOT + 16) * 2);
    (void)ws_size; (void)in_sizes; (void)n_in; (void)out_size;

    // ---- CSR build: 4 launches (R9 lesson: launches beat grid.sync here)
    k_prep<<<CASTB + NBLK, 256, 0, stream>>>(W1l, W1r, W2l, W2r,
                                             w1lT, w1rT, w2lT, w2rT,
                                             csr_src, rowstart, ei, part);
    k_scan_one<<<1, 256, 0, stream>>>(part);
    k_bscatter<<<NBLK, 256, 0, stream>>>(ei, part, pairs);
    k_nfinal<<<NBUCK, 256, 0, stream>>>(pairs, part, rowstart, csr_src);

    // ---- dense pipeline
    const int gm = (NNODES + 63) / 64;                  // 782
    dim3 g1(gm, 2);
    k_gemm_x1<<<g1, 256, 0, stream>>>(x, w1lT, w1rT, xl1, xr1, NNODES);
    k_node1<<<NNODES, 64, 0, stream>>>(xl1, xr1, rowstart, csr_src,
                                       att1, b1, ln1g, ln1b, h1b);
    k_gemm_dual<<<gm, 256, 0, stream>>>(h1b, w2lT, w2rT, xl2, xr2, NNODES);
    k_node2<<<NNODES, 64, 0, stream>>>(xl2, xr2, rowstart, csr_src,
                                       att2, b2, ln2g, ln2b, out);
}

// Round 11
// 277.315 us; speedup vs baseline: 1.6215x; 1.0578x over previous
//
#include <hip/hip_runtime.h>
#include <hip/hip_bf16.h>

#define NNODES 50000
#define NEDGES 800000
#define ETOT   850000
#define NEG_SLOPE 0.2f
#define LN_EPS 1e-5f
#define SM_EPS 1e-16f
#define NBUCK 196                 // ceil(50000/256) buckets of 256 nodes
#define NBLK 208                  // ceil(850000/4096) edge chunks
#define CHUNK 4096
#define CASTB 544                 // cast blocks inside k_prep

typedef short bf16x8 __attribute__((ext_vector_type(8)));
typedef float f32x4  __attribute__((ext_vector_type(4)));
typedef float v2f    __attribute__((ext_vector_type(2)));

__device__ __forceinline__ unsigned pack_bf2(float a, float b) {
    __hip_bfloat162 p;
    p.x = __float2bfloat16(a);
    p.y = __float2bfloat16(b);
    return *reinterpret_cast<unsigned*>(&p);
}

__device__ __forceinline__ v2f bf2_to_f2(unsigned u) {
    v2f r;
    r.x = __int_as_float((int)(u << 16));
    r.y = __int_as_float((int)(u & 0xFFFF0000u));
    return r;
}

template <int CTRL>
__device__ __forceinline__ float dpp_add(float x) {
    return x + __int_as_float(__builtin_amdgcn_update_dpp(
        0, __float_as_int(x), CTRL, 0xF, 0xF, true));
}
__device__ __forceinline__ float red16(float x) {
    x = dpp_add<0xB1>(x);
    x = dpp_add<0x4E>(x);
    x = dpp_add<0x124>(x);
    x = dpp_add<0x128>(x);
    return x;
}

__device__ __forceinline__ float edot2(v2f x01, v2f x23, v2f xr01, v2f xr23,
                                       v2f a01, v2f a23) {
    v2f s01 = x01 + xr01;
    v2f s23 = x23 + xr23;
    v2f t01 = __builtin_elementwise_max(s01, s01 * NEG_SLOPE);
    v2f t23 = __builtin_elementwise_max(s23, s23 * NEG_SLOPE);
    v2f d = t01 * a01 + t23 * a23;
    return d.x + d.y;
}

// XOR-swizzled LDS offset for 64-col short tiles (16B granules)
__device__ __forceinline__ int sw(int row, int c8) {
    return (row << 6) + ((c8 ^ (row & 7)) << 3);
}

// ---------------- merged prep: weights cast (blocks 0..543) + bucket hist -------
// R9 lesson: launch boundaries beat grid.sync on this part (coop = 1 blk/CU,
// ~30us/sync). R10 lesson: don't serialize the scan onto one block either.
__global__ void __launch_bounds__(256) k_prep(
        const float* __restrict__ W1l, const float* __restrict__ W1r,
        const float* __restrict__ W2l, const float* __restrict__ W2r,
        __hip_bfloat16* __restrict__ w1lT, __hip_bfloat16* __restrict__ w1rT,
        __hip_bfloat16* __restrict__ w2lT, __hip_bfloat16* __restrict__ w2rT,
        unsigned short* __restrict__ csr_src, int* __restrict__ rowstart,
        const int* __restrict__ ei, int* __restrict__ part) {
    __shared__ int h[256];
    if (blockIdx.x < CASTB) {
        int t = blockIdx.x * 256 + threadIdx.x;
        if (t < 16) csr_src[ETOT + t] = 0;       // pad: node-0 reads, weight-masked
        if (t == 16) rowstart[NNODES] = ETOT;    // sentinel
        if (t < 65536) {
            int k = t >> 8, n = t & 255;
            w1lT[n * 256 + k] = __float2bfloat16(W1l[t]);
        } else if (t < 131072) {
            int u = t - 65536; int k = u >> 8, n = u & 255;
            w1rT[n * 256 + k] = __float2bfloat16(W1r[u]);
        } else if (t < 135168) {
            int u = t - 131072; int k = u >> 6, n = u & 63;
            w2lT[n * 64 + k] = __float2bfloat16(W2l[u]);
        } else if (t < 139264) {
            int u = t - 135168; int k = u >> 6, n = u & 63;
            w2rT[n * 64 + k] = __float2bfloat16(W2r[u]);
        }
        return;
    }
    // bucket histogram: LDS only, per-(bucket,chunk) counts
    const int b = blockIdx.x - CASTB;
    h[threadIdx.x] = 0;
    __syncthreads();
    const int base = b * CHUNK;
    #pragma unroll
    for (int it = 0; it < 16; ++it) {
        int e = base + it * 256 + threadIdx.x;
        if (e < ETOT) {
            int dst = (e < NEDGES) ? ei[NEDGES + e] : (e - NEDGES);
            atomicAdd(&h[dst >> 8], 1);
        }
    }
    __syncthreads();
    part[threadIdx.x * NBLK + b] = h[threadIdx.x];   // bucket-major
}

// ---------------- generic block-level exclusive scan (parallel trio) ------------
__global__ void k_scan_blk(const int* __restrict__ in, int n,
                           int* __restrict__ out, int* __restrict__ bsum) {
    __shared__ int s[256];
    int t = threadIdx.x;
    int i = blockIdx.x * 256 + t;
    int v = (i < n) ? in[i] : 0;
    s[t] = v;
    __syncthreads();
    #pragma unroll
    for (int off = 1; off < 256; off <<= 1) {
        int add = (t >= off) ? s[t - off] : 0;
        __syncthreads();
        s[t] += add;
        __syncthreads();
    }
    if (i < n) out[i] = s[t] - v;
    if (t == 255) bsum[blockIdx.x] = s[255];
}

__global__ void k_scan_top(int* __restrict__ bs, int nb) {   // nb <= 256
    __shared__ int s[256];
    int t = threadIdx.x;
    int v = (t < nb) ? bs[t] : 0;
    s[t] = v;
    __syncthreads();
    #pragma unroll
    for (int off = 1; off < 256; off <<= 1) {
        int add = (t >= off) ? s[t - off] : 0;
        __syncthreads();
        s[t] += add;
        __syncthreads();
    }
    if (t < nb) bs[t] = s[t] - v;
}

__global__ void k_scan_add(int* __restrict__ out, const int* __restrict__ bs, int n) {
    int i = blockIdx.x * 256 + threadIdx.x;
    if (i < n) out[i] += bs[i >> 8];
}

// ---------------- bucket scatter: LDS cursors, coalesced-run pair writes --------
__global__ void __launch_bounds__(256) k_bscatter(const int* __restrict__ ei,
                                                  const int* __restrict__ partoff,
                                                  unsigned* __restrict__ pairs) {
    __shared__ int cnt[256];
    const int t = threadIdx.x;
    cnt[t] = partoff[t * NBLK + blockIdx.x];
    __syncthreads();
    const int base = blockIdx.x * CHUNK;
    #pragma unroll
    for (int it = 0; it < 16; ++it) {
        int e = base + it * 256 + t;
        if (e < ETOT) {
            int dst, src;
            if (e < NEDGES) { dst = ei[NEDGES + e]; src = ei[e]; }
            else            { dst = e - NEDGES;     src = dst; }
            int pos = atomicAdd(&cnt[dst >> 8], 1);
            pairs[pos] = ((unsigned)dst << 16) | (unsigned)src;
        }
    }
}

// ---------------- fused per-bucket: count + LDS scan + rowstart + scatter -------
__global__ void __launch_bounds__(256) k_nfinal(const unsigned* __restrict__ pairs,
                                                const int* __restrict__ partoff,
                                                int* __restrict__ rowstart,
                                                unsigned short* __restrict__ csr_src) {
    __shared__ int h[256];
    __shared__ int cur[256];
    const int b = blockIdx.x;
    const int t = threadIdx.x;
    const int r0 = partoff[b * NBLK];
    const int r1 = partoff[(b + 1) * NBLK];
    h[t] = 0;
    __syncthreads();
    for (int i = r0 + t; i < r1; i += 1024) {
        unsigned p0 = pairs[i];
        bool v1 = (i + 256 < r1), v2 = (i + 512 < r1), v3 = (i + 768 < r1);
        unsigned p1 = v1 ? pairs[i + 256] : 0u;
        unsigned p2 = v2 ? pairs[i + 512] : 0u;
        unsigned p3 = v3 ? pairs[i + 768] : 0u;
        atomicAdd(&h[(p0 >> 16) & 255], 1);
        if (v1) atomicAdd(&h[(p1 >> 16) & 255], 1);
        if (v2) atomicAdd(&h[(p2 >> 16) & 255], 1);
        if (v3) atomicAdd(&h[(p3 >> 16) & 255], 1);
    }
    __syncthreads();
    int v = h[t];
    cur[t] = v;
    __syncthreads();
    #pragma unroll
    for (int off = 1; off < 256; off <<= 1) {
        int add = (t >= off) ? cur[t - off] : 0;
        __syncthreads();
        cur[t] += add;
        __syncthreads();
    }
    int start = r0 + cur[t] - v;
    int node = (b << 8) + t;
    if (node < NNODES) rowstart[node] = start;
    cur[t] = start;
    __syncthreads();
    for (int i = r0 + t; i < r1; i += 1024) {
        unsigned p0 = pairs[i];
        bool v1 = (i + 256 < r1), v2 = (i + 512 < r1), v3 = (i + 768 < r1);
        unsigned p1 = v1 ? pairs[i + 256] : 0u;
        unsigned p2 = v2 ? pairs[i + 512] : 0u;
        unsigned p3 = v3 ? pairs[i + 768] : 0u;
        int q0 = atomicAdd(&cur[(p0 >> 16) & 255], 1);
        csr_src[q0] = (unsigned short)(p0 & 0xFFFFu);
        if (v1) { int q = atomicAdd(&cur[(p1 >> 16) & 255], 1); csr_src[q] = (unsigned short)(p1 & 0xFFFFu); }
        if (v2) { int q = atomicAdd(&cur[(p2 >> 16) & 255], 1); csr_src[q] = (unsigned short)(p2 & 0xFFFFu); }
        if (v3) { int q = atomicAdd(&cur[(p3 >> 16) & 255], 1); csr_src[q] = (unsigned short)(p3 & 0xFFFFu); }
    }
}

// ---------------- layer-1 GEMM: f32 A cast in-stage, 2 n-slices/block ----------
// 40KB LDS -> 4 blocks/CU. Round-5 lesson: 72KB single-pass = occupancy cliff.
__global__ __launch_bounds__(256) void k_gemm_x1(
    const float* __restrict__ X,
    const __hip_bfloat16* __restrict__ WTl,
    const __hip_bfloat16* __restrict__ WTr,
    __hip_bfloat16* __restrict__ Cl,
    __hip_bfloat16* __restrict__ Cr, int M)
{
    __shared__ short As[64 * 64];
    __shared__ short Bls[2][64 * 64];
    __shared__ short Brs[2][64 * 64];
    const int t = threadIdx.x;
    const int m0 = blockIdx.x * 64;
    const int nb = blockIdx.y * 128;     // n-slice base
    const int wave = t >> 6, lane = t & 63;
    const int wm = wave & 1, wn = wave >> 1;
    const int l15 = lane & 15, quad = lane >> 4;

    f32x4 accl[2][2][2] = {};
    f32x4 accr[2][2][2] = {};
    for (int k0 = 0; k0 < 256; k0 += 64) {
        __syncthreads();
        #pragma unroll
        for (int it = 0; it < 2; ++it) {
            int f = t + 256 * it;
            int r = f >> 3, c8 = f & 7;
            int row = m0 + r;
            uint4 v = make_uint4(0u, 0u, 0u, 0u);
            if (row < M) {
                const float4* src = reinterpret_cast<const float4*>(
                    X + (size_t)row * 256 + k0 + c8 * 8);
                float4 a = src[0], b = src[1];
                v.x = pack_bf2(a.x, a.y);
                v.y = pack_bf2(a.z, a.w);
                v.z = pack_bf2(b.x, b.y);
                v.w = pack_bf2(b.z, b.w);
            }
            *reinterpret_cast<uint4*>(&As[sw(r, c8)]) = v;
        }
        #pragma unroll
        for (int it = 0; it < 4; ++it) {
            int f = t + 256 * it;                 // 0..1023
            int s = f >> 9, ws = f & 511;
            int n = ws >> 3, c8 = ws & 7;
            int ng = nb + s * 64 + n;
            *reinterpret_cast<uint4*>(&Bls[s][sw(n, c8)]) =
                *reinterpret_cast<const uint4*>(&WTl[(size_t)ng * 256 + k0 + c8 * 8]);
            *reinterpret_cast<uint4*>(&Brs[s][sw(n, c8)]) =
                *reinterpret_cast<const uint4*>(&WTr[(size_t)ng * 256 + k0 + c8 * 8]);
        }
        __syncthreads();
        #pragma unroll
        for (int kk8 = 0; kk8 < 8; kk8 += 4) {
            bf16x8 af[2];
            #pragma unroll
            for (int mi = 0; mi < 2; ++mi)
                af[mi] = *reinterpret_cast<const bf16x8*>(
                    &As[sw(wm * 32 + mi * 16 + l15, kk8 + quad)]);
            #pragma unroll
            for (int s = 0; s < 2; ++s) {
                bf16x8 bl[2], br[2];
                #pragma unroll
                for (int ni = 0; ni < 2; ++ni) {
                    int rB = wn * 32 + ni * 16 + l15;
                    bl[ni] = *reinterpret_cast<const bf16x8*>(&Bls[s][sw(rB, kk8 + quad)]);
                    br[ni] = *reinterpret_cast<const bf16x8*>(&Brs[s][sw(rB, kk8 + quad)]);
                }
                #pragma unroll
                for (int mi = 0; mi < 2; ++mi)
                    #pragma unroll
                    for (int ni = 0; ni < 2; ++ni) {
                        accl[s][mi][ni] = __builtin_amdgcn_mfma_f32_16x16x32_bf16(
                            af[mi], bl[ni], accl[s][mi][ni], 0, 0, 0);
                        accr[s][mi][ni] = __builtin_amdgcn_mfma_f32_16x16x32_bf16(
                            af[mi], br[ni], accr[s][mi][ni], 0, 0, 0);
                    }
            }
        }
    }
    #pragma unroll
    for (int s = 0; s < 2; ++s)
        #pragma unroll
        for (int mi = 0; mi < 2; ++mi)
            #pragma unroll
            for (int ni = 0; ni < 2; ++ni)
                #pragma unroll
                for (int r = 0; r < 4; ++r) {
                    int row = m0 + wm * 32 + mi * 16 + quad * 4 + r;
                    int col = nb + s * 64 + wn * 32 + ni * 16 + l15;
                    if (row < M) {
                        Cl[(size_t)row * 256 + col] = __float2bfloat16(accl[s][mi][ni][r]);
                        Cr[(size_t)row * 256 + col] = __float2bfloat16(accr[s][mi][ni][r]);
                    }
                }
}

// ---------------- layer-2 GEMM (bf16 A, N=64) -----------------------------------
__global__ __launch_bounds__(256) void k_gemm_dual(
    const __hip_bfloat16* __restrict__ A,
    const __hip_bfloat16* __restrict__ WTl,
    const __hip_bfloat16* __restrict__ WTr,
    __hip_bfloat16* __restrict__ Cl,
    __hip_bfloat16* __restrict__ Cr, int M)
{
    __shared__ short As[64 * 64];
    __shared__ short Bls[64 * 64];
    __shared__ short Brs[64 * 64];
    const int t = threadIdx.x;
    const int m0 = blockIdx.x * 64;
    const int wave = t >> 6, lane = t & 63;
    const int wm = wave & 1, wn = wave >> 1;
    const int l15 = lane & 15, quad = lane >> 4;

    f32x4 accl[2][2] = {};
    f32x4 accr[2][2] = {};
    {
        #pragma unroll
        for (int it = 0; it < 2; ++it) {
            int f = t + 256 * it;
            int r = f >> 3, c8 = f & 7;
            int row = m0 + r;
            uint4 v = make_uint4(0u, 0u, 0u, 0u);
            if (row < M) v = *reinterpret_cast<const uint4*>(&A[(size_t)row * 64 + c8 * 8]);
            *reinterpret_cast<uint4*>(&As[sw(r, c8)]) = v;
        }
        #pragma unroll
        for (int it = 0; it < 2; ++it) {
            int f = t + 256 * it;
            int n = f >> 3, c8 = f & 7;
            *reinterpret_cast<uint4*>(&Bls[sw(n, c8)]) =
                *reinterpret_cast<const uint4*>(&WTl[(size_t)n * 64 + c8 * 8]);
            *reinterpret_cast<uint4*>(&Brs[sw(n, c8)]) =
                *reinterpret_cast<const uint4*>(&WTr[(size_t)n * 64 + c8 * 8]);
        }
        __syncthreads();
        #pragma unroll
        for (int kk8 = 0; kk8 < 8; kk8 += 4) {
            bf16x8 af[2], bl[2], br[2];
            #pragma unroll
            for (int mi = 0; mi < 2; ++mi)
                af[mi] = *reinterpret_cast<const bf16x8*>(
                    &As[sw(wm * 32 + mi * 16 + l15, kk8 + quad)]);
            #pragma unroll
            for (int ni = 0; ni < 2; ++ni) {
                int rB = wn * 32 + ni * 16 + l15;
                bl[ni] = *reinterpret_cast<const bf16x8*>(&Bls[sw(rB, kk8 + quad)]);
                br[ni] = *reinterpret_cast<const bf16x8*>(&Brs[sw(rB, kk8 + quad)]);
            }
            #pragma unroll
            for (int mi = 0; mi < 2; ++mi)
                #pragma unroll
                for (int ni = 0; ni < 2; ++ni) {
                    accl[mi][ni] = __builtin_amdgcn_mfma_f32_16x16x32_bf16(
                        af[mi], bl[ni], accl[mi][ni], 0, 0, 0);
                    accr[mi][ni] = __builtin_amdgcn_mfma_f32_16x16x32_bf16(
                        af[mi], br[ni], accr[mi][ni], 0, 0, 0);
                }
        }
    }
    #pragma unroll
    for (int mi = 0; mi < 2; ++mi)
        #pragma unroll
        for (int ni = 0; ni < 2; ++ni)
            #pragma unroll
            for (int r = 0; r < 4; ++r) {
                int row = m0 + wm * 32 + mi * 16 + quad * 4 + r;
                int col = wn * 32 + ni * 16 + l15;
                if (row < M) {
                    Cl[(size_t)row * 64 + col] = __float2bfloat16(accl[mi][ni][r]);
                    Cr[(size_t)row * 64 + col] = __float2bfloat16(accr[mi][ni][r]);
                }
            }
}

// ---------------- layer 1: one node per 64-thread wave (R4-exact: 4 edges in
// flight, uint2 8B/lane, VGPR 32, 73% occ, 69.6us — measured-best; R8: 8-deep
// grew in-flight gather set -> FETCH +22MB -> slower) ---------------------------
__global__ void __launch_bounds__(64) k_node1(
                        const __hip_bfloat16* __restrict__ xl,
                        const __hip_bfloat16* __restrict__ xr,
                        const int* __restrict__ rowstart,
                        const unsigned short* __restrict__ csr_src,
                        const float* __restrict__ att,   // [4,64]
                        const float* __restrict__ bias,  // [64]
                        const float* __restrict__ lng,
                        const float* __restrict__ lnb,
                        __hip_bfloat16* __restrict__ h1b) {
    const int i = blockIdx.x;
    const int lane = threadIdx.x;
    const int grp = lane >> 4;
    const int c0 = (lane & 15) * 4;
    const int fb = lane * 4;

    uint2 rraw = *reinterpret_cast<const uint2*>(xr + (size_t)i * 256 + fb);
    v2f xr01 = bf2_to_f2(rraw.x), xr23 = bf2_to_f2(rraw.y);
    const float4 av = *reinterpret_cast<const float4*>(att + fb);
    v2f a01 = {av.x, av.y}, a23 = {av.z, av.w};

    v2f Lab = {0.f, 0.f}, Lcd = {0.f, 0.f};
    v2f Aa01 = {0.f, 0.f}, Aa23 = {0.f, 0.f};
    v2f Ab01 = {0.f, 0.f}, Ab23 = {0.f, 0.f};

    const int p0 = rowstart[i], p1 = rowstart[i + 1];
    for (int p = p0; p < p1; p += 4) {
        int j0 = csr_src[p];
        int j1 = csr_src[p + 1];   // pad-safe
        int j2 = csr_src[p + 2];
        int j3 = csr_src[p + 3];
        uint2 g0 = *reinterpret_cast<const uint2*>(xl + (size_t)j0 * 256 + fb);
        uint2 g1 = *reinterpret_cast<const uint2*>(xl + (size_t)j1 * 256 + fb);
        uint2 g2 = *reinterpret_cast<const uint2*>(xl + (size_t)j2 * 256 + fb);
        uint2 g3 = *reinterpret_cast<const uint2*>(xl + (size_t)j3 * 256 + fb);
        v2f x001 = bf2_to_f2(g0.x), x023 = bf2_to_f2(g0.y);
        v2f x101 = bf2_to_f2(g1.x), x123 = bf2_to_f2(g1.y);
        v2f x201 = bf2_to_f2(g2.x), x223 = bf2_to_f2(g2.y);
        v2f x301 = bf2_to_f2(g3.x), x323 = bf2_to_f2(g3.y);
        float e0 = red16(edot2(x001, x023, xr01, xr23, a01, a23));
        float e1 = red16(edot2(x101, x123, xr01, xr23, a01, a23));
        float e2 = red16(edot2(x201, x223, xr01, xr23, a01, a23));
        float e3 = red16(edot2(x301, x323, xr01, xr23, a01, a23));
        float pe0 = __expf(fminf(e0, 60.f));
        float pe1 = (p + 1 < p1) ? __expf(fminf(e1, 60.f)) : 0.f;
        float pe2 = (p + 2 < p1) ? __expf(fminf(e2, 60.f)) : 0.f;
        float pe3 = (p + 3 < p1) ? __expf(fminf(e3, 60.f)) : 0.f;
        Lab += (v2f){pe0, pe1};
        Lcd += (v2f){pe2, pe3};
        Aa01 += x001 * pe0; Aa23 += x023 * pe0;
        Ab01 += x101 * pe1; Ab23 += x123 * pe1;
        Aa01 += x201 * pe2; Aa23 += x223 * pe2;
        Ab01 += x301 * pe3; Ab23 += x323 * pe3;
    }
    float l = (Lab.x + Lab.y) + (Lcd.x + Lcd.y);
    float inv = 1.f / (l + SM_EPS);
    v2f V01 = (Aa01 + Ab01) * inv;
    v2f V23 = (Aa23 + Ab23) * inv;
    float v0 = V01.x, v1 = V01.y, v2 = V23.x, v3 = V23.y;
    v0 += __shfl_xor(v0, 16); v0 += __shfl_xor(v0, 32);
    v1 += __shfl_xor(v1, 16); v1 += __shfl_xor(v1, 32);
    v2 += __shfl_xor(v2, 16); v2 += __shfl_xor(v2, 32);
    v3 += __shfl_xor(v3, 16); v3 += __shfl_xor(v3, 32);
    const float4 bv = *reinterpret_cast<const float4*>(bias + c0);
    float o0 = v0 * 0.25f + bv.x;
    float o1 = v1 * 0.25f + bv.y;
    float o2 = v2 * 0.25f + bv.z;
    float o3 = v3 * 0.25f + bv.w;
    float mu = red16(o0 + o1 + o2 + o3) * 0.015625f;
    float d0 = o0 - mu, d1 = o1 - mu, d2 = o2 - mu, d3 = o3 - mu;
    float ss = red16(d0 * d0 + d1 * d1 + d2 * d2 + d3 * d3);
    float istd = rsqrtf(ss * 0.015625f + LN_EPS);
    const float4 gv = *reinterpret_cast<const float4*>(lng + c0);
    const float4 bb = *reinterpret_cast<const float4*>(lnb + c0);
    float h0 = fmaxf(d0 * istd * gv.x + bb.x, 0.f);
    float h1 = fmaxf(d1 * istd * gv.y + bb.y, 0.f);
    float h2 = fmaxf(d2 * istd * gv.z + bb.z, 0.f);
    float h3 = fmaxf(d3 * istd * gv.w + bb.w, 0.f);
    if (grp == 0) {
        uint2 pk;
        pk.x = pack_bf2(h0, h1);
        pk.y = pack_bf2(h2, h3);
        *reinterpret_cast<uint2*>(h1b + (size_t)i * 64 + c0) = pk;
    }
}

// ---------------- layer 2: one node per 64-thread wave (R4 structure) ----------
__global__ void __launch_bounds__(64) k_node2(
                        const __hip_bfloat16* __restrict__ xl,
                        const __hip_bfloat16* __restrict__ xr,
                        const int* __restrict__ rowstart,
                        const unsigned short* __restrict__ csr_src,
                        const float* __restrict__ att,   // [64]
                        const float* __restrict__ bias,
                        const float* __restrict__ lng,
                        const float* __restrict__ lnb,
                        float* __restrict__ out) {
    const int i = blockIdx.x;
    const int lane = threadIdx.x;
    const int grp = lane >> 4;
    const int c0 = (lane & 15) * 4;

    uint2 rraw = *reinterpret_cast<const uint2*>(xr + (size_t)i * 64 + c0);
    v2f xr01 = bf2_to_f2(rraw.x), xr23 = bf2_to_f2(rraw.y);
    const float4 avf = *reinterpret_cast<const float4*>(att + c0);
    v2f a01 = {avf.x, avf.y}, a23 = {avf.z, avf.w};
    float l = 0.f;
    v2f A01 = {0.f, 0.f}, A23 = {0.f, 0.f};

    const char* rowbase = (const char*)xl + c0 * 2;
    const int p0 = rowstart[i], p1 = rowstart[i + 1];
    for (int p = p0; p < p1; p += 4) {
        int pe = p + grp;
        int j = csr_src[pe];                          // pad-safe
        uint2 g = *reinterpret_cast<const uint2*>(rowbase + ((size_t)j << 7));
        v2f x01 = bf2_to_f2(g.x), x23 = bf2_to_f2(g.y);
        float e = red16(edot2(x01, x23, xr01, xr23, a01, a23));
        float w = (pe < p1) ? __expf(fminf(e, 60.f)) : 0.f;
        l += w;
        A01 += x01 * w;
        A23 += x23 * w;
    }
    #pragma unroll
    for (int s = 16; s <= 32; s <<= 1) {
        l     += __shfl_xor(l, s);
        A01.x += __shfl_xor(A01.x, s);
        A01.y += __shfl_xor(A01.y, s);
        A23.x += __shfl_xor(A23.x, s);
        A23.y += __shfl_xor(A23.y, s);
    }
    float inv = 1.f / (l + SM_EPS);
    const float4 bv = *reinterpret_cast<const float4*>(bias + c0);
    float o0 = A01.x * inv + bv.x;
    float o1 = A01.y * inv + bv.y;
    float o2 = A23.x * inv + bv.z;
    float o3 = A23.y * inv + bv.w;
    float mu = red16(o0 + o1 + o2 + o3) * 0.015625f;
    float d0 = o0 - mu, d1 = o1 - mu, d2 = o2 - mu, d3 = o3 - mu;
    float ss = red16(d0 * d0 + d1 * d1 + d2 * d2 + d3 * d3);
    float istd = rsqrtf(ss * 0.015625f + LN_EPS);
    const float4 gv = *reinterpret_cast<const float4*>(lng + c0);
    const float4 bb = *reinterpret_cast<const float4*>(lnb + c0);
    if (grp == 0) {
        float4 y;
        y.x = d0 * istd * gv.x + bb.x;
        y.y = d1 * istd * gv.y + bb.y;
        y.z = d2 * istd * gv.z + bb.z;
        y.w = d3 * istd * gv.w + bb.w;
        *reinterpret_cast<float4*>(out + (size_t)i * 64 + c0) = y;
    }
}

extern "C" void kernel_launch(void* const* d_in, const int* in_sizes, int n_in,
                              void* d_out, int out_size, void* d_ws, size_t ws_size,
                              hipStream_t stream) {
    const float* x    = (const float*)d_in[0];
    const int*   ei   = (const int*)d_in[1];
    const float* W1l  = (const float*)d_in[2];
    const float* W1r  = (const float*)d_in[3];
    const float* att1 = (const float*)d_in[4];
    const float* b1   = (const float*)d_in[5];
    const float* ln1g = (const float*)d_in[6];
    const float* ln1b = (const float*)d_in[7];
    const float* W2l  = (const float*)d_in[8];
    const float* W2r  = (const float*)d_in[9];
    const float* att2 = (const float*)d_in[10];
    const float* b2   = (const float*)d_in[11];
    const float* ln2g = (const float*)d_in[12];
    const float* ln2b = (const float*)d_in[13];
    float* out = (float*)d_out;

    char* w = (char*)d_ws;
    size_t off = 0;
    auto alloc = [&](size_t bytes) -> void* {
        void* p = w + off;
        off += (bytes + 255) & ~(size_t)255;
        return p;
    };
    __hip_bfloat16* xl1  = (__hip_bfloat16*)alloc((size_t)NNODES * 256 * 2);
    __hip_bfloat16* xr1  = (__hip_bfloat16*)alloc((size_t)NNODES * 256 * 2);
    __hip_bfloat16* h1b  = (__hip_bfloat16*)alloc((size_t)NNODES * 64 * 2);
    __hip_bfloat16* xl2  = (__hip_bfloat16*)alloc((size_t)NNODES * 64 * 2);
    __hip_bfloat16* xr2  = (__hip_bfloat16*)alloc((size_t)NNODES * 64 * 2);
    __hip_bfloat16* w1lT = (__hip_bfloat16*)alloc(256 * 256 * 2);
    __hip_bfloat16* w1rT = (__hip_bfloat16*)alloc(256 * 256 * 2);
    __hip_bfloat16* w2lT = (__hip_bfloat16*)alloc(64 * 64 * 2);
    __hip_bfloat16* w2rT = (__hip_bfloat16*)alloc(64 * 64 * 2);
    int* part     = (int*)alloc((size_t)256 * NBLK * 4);       // per-(bucket,chunk)
    unsigned* pairs = (unsigned*)alloc((size_t)ETOT * 4);
    int* rowstart = (int*)alloc((size_t)(NNODES + 1) * 4);
    unsigned short* csr_src = (unsigned short*)alloc((size_t)(ETOT + 16) * 2);
    int* blocksum = (int*)alloc(1024);
    (void)ws_size; (void)in_sizes; (void)n_in; (void)out_size;

    // ---- CSR build (R11 = R8 structure: parallel scan trio, merged prep)
    k_prep<<<CASTB + NBLK, 256, 0, stream>>>(W1l, W1r, W2l, W2r,
                                             w1lT, w1rT, w2lT, w2rT,
                                             csr_src, rowstart, ei, part);
    const int partN = 256 * NBLK;                       // 53248
    k_scan_blk<<<partN / 256, 256, 0, stream>>>(part, partN, part, blocksum);
    k_scan_top<<<1, 256, 0, stream>>>(blocksum, partN / 256);
    k_scan_add<<<partN / 256, 256, 0, stream>>>(part, blocksum, partN);
    k_bscatter<<<NBLK, 256, 0, stream>>>(ei, part, pairs);
    k_nfinal<<<NBUCK, 256, 0, stream>>>(pairs, part, rowstart, csr_src);

    // ---- dense pipeline
    const int gm = (NNODES + 63) / 64;                  // 782
    dim3 g1(gm, 2);
    k_gemm_x1<<<g1, 256, 0, stream>>>(x, w1lT, w1rT, xl1, xr1, NNODES);
    k_node1<<<NNODES, 64, 0, stream>>>(xl1, xr1, rowstart, csr_src,
                                       att1, b1, ln1g, ln1b, h1b);
    k_gemm_dual<<<gm, 256, 0, stream>>>(h1b, w2lT, w2rT, xl2, xr2, NNODES);
    k_node2<<<NNODES, 64, 0, stream>>>(xl2, xr2, rowstart, csr_src,
                                       att2, b2, ln2g, ln2b, out);
}